// Round 9
// baseline (1157.457 us; speedup 1.0000x reference)
//
#include <hip/hip_runtime.h>
#include <hip/hip_bf16.h>
#include <stdint.h>

// SJ_SNN: bit-exact replica of the golden (jax on CPU -> XLA/Eigen fp32):
// per output element the contraction is a SINGLE accumulator, ascending k,
// true FMA. PASS r6..r12/r16 (absmax 0.00390625 = golden bf16 floor).
// r17 = r16 + GEMM thread-tile 8x8 -> 16x8 (block tile 128x128 -> 256x128).
// Rationale: r16 GEMM is LDS-issue bound (4 ds_read_b128 / 64 FMA; model
// 328us ~ measured 401us x1.22). 16x8 = 6 b128 / 128 FMA -> model 246us,
// FMA wall 218us -> expect ~300-330us.
// r7's 8x8 failure modes addressed analytically:
//  - reads stay conflict-free under G=(col>>2)^(col>>5)^(k>>3): wave A-read
//    quads = 4(s&1)^(s>>1)^K (8 distinct), B-read quads = (2u+j)^(u>>2)^K'
//    (8 distinct). Derived, not assumed.
//  - VGPR: acc[16][8]=128 + ~45 -> __launch_bounds__(256,2) (cap 256, no
//    spill; 2 blocks/CU x 50KB LDS = 100KB < 160KB).
// Epilogue: r10-style LDS-staged coalesced stores, 4 rounds of 64x128
// through a unioned LDS buffer (write ~2-way conflicts = free; reads clean).

__global__ void k_zero(unsigned int* __restrict__ p, int n){
  int i = blockIdx.x * 256 + threadIdx.x;
  if (i < n) p[i] = 0u;
}

// out[C][R] = in[R][C]  (exact fp32 copy)
__global__ void k_transpose(const float* __restrict__ in, float* __restrict__ out, int R, int C){
  __shared__ float tile[32][33];
  int bx = blockIdx.x * 32, by = blockIdx.y * 32;
  int tx = threadIdx.x, ty = threadIdx.y;
  for (int i = ty; i < 32; i += 8)
    tile[i][tx] = in[(size_t)(by + i) * C + bx + tx];
  __syncthreads();
  for (int i = ty; i < 32; i += 8)
    out[(size_t)(bx + i) * R + by + tx] = tile[tx][i];
}

// Layer-0 GEMM, Eigen order: C[m][e] = (single ascending FMA chain over
// k=0..511 of x[m][k]*W0[e][k]) + bias[e].
// 256(m) x 128(n) block tile, 16x8 per thread, 256 threads.
// Lane remap: c = tid bits {0,1,2,6} (8 cols), r = tid bits {3,4,5,7}
// (16 rows). As = [32 k][260] (cols 0..255), Bs = [32 k][132] (cols 0..127);
// slot(k,col) = G*4 + (col&3), G = (col>>2)^(col>>5)^(k>>3).
__global__ __launch_bounds__(256, 2) void k_gemm_np(const float* __restrict__ A,
    const float* __restrict__ Bw, const float* __restrict__ bias,
    float* __restrict__ C, int M){
  (void)M;
  __shared__ float LDS[32 * 260 + 32 * 132];
  float* As = LDS;                 // [32][260]
  float* Bs = LDS + 32 * 260;      // [32][132]
  int bm = blockIdx.y * 256;
  int bn = blockIdx.x * 128;
  int tid = threadIdx.x;
  int kk = tid & 31, q = tid >> 5;                 // staging decode (q 0..7)
  int c = (tid & 7) | ((tid & 64) >> 3);           // 0..15
  int r = ((tid >> 3) & 7) | ((tid & 128) >> 4);   // 0..15
  int gA = (4 * r) ^ (r >> 1);                     // G(k=0, col=r*16)
  int gB = (2 * c) ^ (c >> 2);                     // G(k=0, col=c*8)
  float acc[16][8];
#pragma unroll
  for (int ii = 0; ii < 16; ++ii)
#pragma unroll
    for (int jj = 0; jj < 8; ++jj) acc[ii][jj] = 0.f;

  for (int k0 = 0; k0 < 512; k0 += 32){
    // stage A: 8 col-groups of 4 (cols 0..255)
#pragma unroll
    for (int rr = 0; rr < 8; ++rr){
      int colb = q * 4 + rr * 32;                  // 4-aligned, 0..252
      int gi = (colb >> 2) ^ (colb >> 5) ^ (kk >> 3);
      float4 va;
      va.x = A[(size_t)(bm + colb + 0) * 512 + k0 + kk];
      va.y = A[(size_t)(bm + colb + 1) * 512 + k0 + kk];
      va.z = A[(size_t)(bm + colb + 2) * 512 + k0 + kk];
      va.w = A[(size_t)(bm + colb + 3) * 512 + k0 + kk];
      *(float4*)&As[kk * 260 + (gi << 2)] = va;
    }
    // stage B: 4 col-groups of 4 (cols 0..127)
#pragma unroll
    for (int rr = 0; rr < 4; ++rr){
      int colb = q * 4 + rr * 32;
      int gi = (colb >> 2) ^ (colb >> 5) ^ (kk >> 3);
      float4 vb;
      vb.x = Bw[(size_t)(bn + colb + 0) * 512 + k0 + kk];
      vb.y = Bw[(size_t)(bn + colb + 1) * 512 + k0 + kk];
      vb.z = Bw[(size_t)(bn + colb + 2) * 512 + k0 + kk];
      vb.w = Bw[(size_t)(bn + colb + 3) * 512 + k0 + kk];
      *(float4*)&Bs[kk * 132 + (gi << 2)] = vb;
    }
    __syncthreads();
    // compute: ascending k overall (kg outer ascending, k8 inner ascending)
#pragma unroll
    for (int kg = 0; kg < 4; ++kg){
      const int sa = (gA ^ kg) << 2;
      const int sb = (gB ^ kg) << 2;
#pragma unroll
      for (int k8 = 0; k8 < 8; ++k8){
        const int k = kg * 8 + k8;
        float4 av0 = *(const float4*)&As[k * 260 + sa];
        float4 av1 = *(const float4*)&As[k * 260 + (sa ^ 4)];
        float4 av2 = *(const float4*)&As[k * 260 + (sa ^ 8)];
        float4 av3 = *(const float4*)&As[k * 260 + (sa ^ 12)];
        float4 bv0 = *(const float4*)&Bs[k * 132 + sb];
        float4 bv1 = *(const float4*)&Bs[k * 132 + (sb ^ 4)];
        float a[16] = {av0.x, av0.y, av0.z, av0.w, av1.x, av1.y, av1.z, av1.w,
                       av2.x, av2.y, av2.z, av2.w, av3.x, av3.y, av3.z, av3.w};
        float b[8]  = {bv0.x, bv0.y, bv0.z, bv0.w, bv1.x, bv1.y, bv1.z, bv1.w};
#pragma unroll
        for (int ii = 0; ii < 16; ++ii)
#pragma unroll
          for (int jj = 0; jj < 8; ++jj)
            acc[ii][jj] = __fmaf_rn(a[ii], b[jj], acc[ii][jj]);
      }
    }
    __syncthreads();
  }

  // Epilogue: bias + LDS-staged coalesced stores. 4 rounds of 64 rows x 128
  // cols through LDS chunk [64][132] (fits 12544-float union). Participating
  // threads in round t: (r>>2)==t; chunk row lr = (r&3)*16 + ii.
  float4 bi0 = *(const float4*)(bias + bn + c * 8);
  float4 bi1 = *(const float4*)(bias + bn + c * 8 + 4);
#pragma unroll
  for (int t = 0; t < 4; ++t){
    if ((r >> 2) == t){
#pragma unroll
      for (int ii = 0; ii < 16; ++ii){
        const int lr = (r & 3) * 16 + ii;
        float4 o0, o1;
        o0.x = __fadd_rn(acc[ii][0], bi0.x);
        o0.y = __fadd_rn(acc[ii][1], bi0.y);
        o0.z = __fadd_rn(acc[ii][2], bi0.z);
        o0.w = __fadd_rn(acc[ii][3], bi0.w);
        o1.x = __fadd_rn(acc[ii][4], bi1.x);
        o1.y = __fadd_rn(acc[ii][5], bi1.y);
        o1.z = __fadd_rn(acc[ii][6], bi1.z);
        o1.w = __fadd_rn(acc[ii][7], bi1.w);
        *(float4*)&LDS[lr * 132 + c * 8]     = o0;
        *(float4*)&LDS[lr * 132 + c * 8 + 4] = o1;
      }
    }
    __syncthreads();
    // read phase: 2048 b128 chunks; per instruction a wave covers 2 rows x
    // 512B contiguous (full lines), LDS quads spread evenly (conflict-free).
#pragma unroll
    for (int u = 0; u < 8; ++u){
      int idx = u * 256 + tid;
      int row = idx >> 5;
      int ch4 = (idx & 31) << 2;
      float4 v = *(const float4*)&LDS[row * 132 + ch4];
      *(float4*)&C[(size_t)(bm + t * 64 + row) * 1024 + bn + ch4] = v;
    }
    __syncthreads();
  }
}

// BN stats: per (chunk, channel), SEQUENTIAL in-order over 256 samples.
__global__ __launch_bounds__(256) void k_stats_np(const float* __restrict__ A,
    float* __restrict__ mu, float* __restrict__ var, int Dch, int c0){
  int cl = blockIdx.x;
  int ch = blockIdx.y * 256 + threadIdx.x;
  const float* base = A + (size_t)cl * 256 * Dch + ch;
  float acc = 0.f;
  for (int s = 0; s < 256; ++s)
    acc = __fadd_rn(acc, base[(size_t)s * Dch]);
  float m = __fmul_rn(acc, 1.f / 256.f);   // /256 exact (pow2)
  float vacc = 0.f;
  for (int s = 0; s < 256; ++s){
    float d = __fsub_rn(base[(size_t)s * Dch], m);
    vacc = __fadd_rn(vacc, __fmul_rn(d, d));
  }
  int c = c0 + cl;
  mu[(size_t)c * Dch + ch]  = m;
  var[(size_t)c * Dch + ch] = __fmul_rn(vacc, 1.f / 256.f);
}

// fp32 BN + LIF scan (hidden layers): spike bitmasks, 64-thread blocks,
// software-pipelined chunk prefetch (8 independent loads in flight).
__global__ __launch_bounds__(64) void k_scan_spike_np(const float* __restrict__ A,
    const float* __restrict__ mu, const float* __restrict__ var,
    const float* __restrict__ g, const float* __restrict__ bt,
    float* __restrict__ vstate, unsigned long long* __restrict__ mask,
    int Dch, int c0, int nb){
  int ebn = Dch >> 6;
  int eb = blockIdx.x % ebn;
  int b  = blockIdx.x / ebn;
  int e  = (eb << 6) + threadIdx.x;
  float gg = g[e], bb = bt[e];
  float v = vstate[(size_t)b * Dch + e];
  float hbuf[8];
#pragma unroll
  for (int t = 0; t < 8; ++t)
    hbuf[t] = A[(size_t)(t * 32 + b) * Dch + e];
  for (int cl = 0; cl < nb; ++cl){
    int c = c0 + cl;
    float m  = mu[(size_t)c * Dch + e];
    float ve = __fadd_rn(var[(size_t)c * Dch + e], 1e-5f);
    float sq = (float)sqrt((double)ve);          // correctly-rounded fp32 sqrt
    float r  = (float)(1.0 / (double)sq);        // correctly-rounded fp32 div
    float hn[8];
    if (cl + 1 < nb){
#pragma unroll
      for (int t = 0; t < 8; ++t)
        hn[t] = A[(size_t)(((cl + 1) * 8 + t) * 32 + b) * Dch + e];
    } else {
#pragma unroll
      for (int t = 0; t < 8; ++t) hn[t] = 0.f;
    }
#pragma unroll
    for (int t = 0; t < 8; ++t){
      int sl = (cl * 8 + t) * 32 + b;
      float xn = __fadd_rn(__fmul_rn(__fmul_rn(gg, __fsub_rn(hbuf[t], m)), r), bb);
      v = __fadd_rn(v, __fmul_rn(__fsub_rn(xn, v), 0.5f));
      bool sp = (v >= 1.0f);                     // == (v-1>=0)
      unsigned long long bal = __ballot(sp);
      if (sp) v = 0.0f;
      if (threadIdx.x == 0) mask[(size_t)sl * 16 + eb] = bal;
    }
#pragma unroll
    for (int t = 0; t < 8; ++t) hbuf[t] = hn[t];
  }
  vstate[(size_t)b * Dch + e] = v;
}

// Sparse spike linear, Eigen order. Wave-cooperative list extraction:
// 16 lanes popcount their 64-bit mask word, __shfl exclusive prefix-scan,
// then parallel ascending writes into LDS. List order identical to the old
// serial scan -> single-accumulator ascending add chain preserved exactly.
// Consume loop: 8 weight rows in flight.
__global__ __launch_bounds__(256) void k_sparse_np(const unsigned long long* __restrict__ mask,
    const float* __restrict__ WT, const float* __restrict__ bias,
    float* __restrict__ C, int Dout){
  int tid = threadIdx.x;
  int lane = tid & 63;
  int wid = tid >> 6;
  int wps = Dout >> 8;            // waves per sample: 4 (1024) or 2 (512)
  int chgrp = wid % wps;
  int sgrp  = wid / wps;
  int spb   = 4 / wps;            // samples per block
  int s = blockIdx.x * spb + sgrp;
  int ch = (chgrp << 8) + (lane << 2);
  __shared__ unsigned short list[2][1024];
  __shared__ int nlist[2];

  if (chgrp == 0 && lane < 16){
    unsigned long long mw = mask[(size_t)s * 16 + lane];
    int cnt = __popcll(mw);
    int base = 0;
#pragma unroll
    for (int w = 0; w < 16; ++w){
      int cw = __shfl(cnt, w, 64);
      base += (w < lane) ? cw : 0;
    }
    int idx = base;
    while (mw){
      int bit = __ffsll(mw) - 1;
      mw &= mw - 1;
      list[sgrp][idx++] = (unsigned short)((lane << 6) + bit);
    }
    if (lane == 15) nlist[sgrp] = base + cnt;
  }
  __syncthreads();
  int n = nlist[sgrp];
  const unsigned short* il = list[sgrp];
  float a0 = 0.f, a1 = 0.f, a2 = 0.f, a3 = 0.f;
  int i = 0;
  for (; i + 8 <= n; i += 8){
    float4 wv[8];
#pragma unroll
    for (int u = 0; u < 8; ++u)
      wv[u] = *(const float4*)(WT + (size_t)il[i + u] * Dout + ch);
#pragma unroll
    for (int u = 0; u < 8; ++u){
      a0 = __fadd_rn(a0, wv[u].x); a1 = __fadd_rn(a1, wv[u].y);
      a2 = __fadd_rn(a2, wv[u].z); a3 = __fadd_rn(a3, wv[u].w);
    }
  }
  for (; i < n; ++i){
    int d = il[i];
    float4 wv = *(const float4*)(WT + (size_t)d * Dout + ch);
    a0 = __fadd_rn(a0, wv.x); a1 = __fadd_rn(a1, wv.y); a2 = __fadd_rn(a2, wv.z); a3 = __fadd_rn(a3, wv.w);
  }
  float4 bb = *(const float4*)(bias + ch);
  float4 o;
  o.x = __fadd_rn(a0, bb.x);
  o.y = __fadd_rn(a1, bb.y);
  o.z = __fadd_rn(a2, bb.z);
  o.w = __fadd_rn(a3, bb.w);
  *(float4*)(C + (size_t)s * Dout + ch) = o;
}

// Last layer: fp32 leaky integrator; sequential mean over 8 timesteps,
// /8 exact; float32 out. 64-thread blocks + chunk prefetch.
__global__ __launch_bounds__(64) void k_scan_last_np(const float* __restrict__ A,
    const float* __restrict__ mu, const float* __restrict__ var,
    const float* __restrict__ g, const float* __restrict__ bt,
    float* __restrict__ vstate, float* __restrict__ out, int c0, int nb){
  const int Dch = 512;
  int eb = blockIdx.x & 7;
  int b  = blockIdx.x >> 3;
  int e  = (eb << 6) + threadIdx.x;
  float gg = g[e], bb = bt[e];
  float v = vstate[(size_t)b * Dch + e];
  float hbuf[8];
#pragma unroll
  for (int t = 0; t < 8; ++t)
    hbuf[t] = A[(size_t)(t * 32 + b) * Dch + e];
  for (int cl = 0; cl < nb; ++cl){
    int c = c0 + cl;
    float m  = mu[(size_t)c * Dch + e];
    float ve = __fadd_rn(var[(size_t)c * Dch + e], 1e-5f);
    float sq = (float)sqrt((double)ve);
    float r  = (float)(1.0 / (double)sq);
    float hn[8];
    if (cl + 1 < nb){
#pragma unroll
      for (int t = 0; t < 8; ++t)
        hn[t] = A[(size_t)(((cl + 1) * 8 + t) * 32 + b) * Dch + e];
    } else {
#pragma unroll
      for (int t = 0; t < 8; ++t) hn[t] = 0.f;
    }
    float macc = 0.f;
#pragma unroll
    for (int t = 0; t < 8; ++t){
      float xn = __fadd_rn(__fmul_rn(__fmul_rn(gg, __fsub_rn(hbuf[t], m)), r), bb);
      v = __fadd_rn(v, __fmul_rn(__fsub_rn(xn, v), 0.5f));
      macc = __fadd_rn(macc, v);
    }
    out[((size_t)c * 32 + b) * 512 + e] = __fmul_rn(macc, 0.125f);
#pragma unroll
    for (int t = 0; t < 8; ++t) hbuf[t] = hn[t];
  }
  vstate[(size_t)b * Dch + e] = v;
}

static inline size_t al256(size_t x){ return (x + 255) & ~(size_t)255; }

extern "C" void kernel_launch(void* const* d_in, const int* in_sizes, int n_in,
                              void* d_out, int out_size, void* d_ws, size_t ws_size,
                              hipStream_t stream){
  (void)in_sizes; (void)n_in; (void)out_size;
  const float* x   = (const float*)d_in[0];
  const float* W0  = (const float*)d_in[1];
  const float* b0  = (const float*)d_in[2];
  const float* g0  = (const float*)d_in[3];
  const float* bt0 = (const float*)d_in[4];
  const float* W1  = (const float*)d_in[5];
  const float* b1  = (const float*)d_in[6];
  const float* g1  = (const float*)d_in[7];
  const float* bt1 = (const float*)d_in[8];
  const float* W2  = (const float*)d_in[9];
  const float* b2  = (const float*)d_in[10];
  const float* g2  = (const float*)d_in[11];
  const float* bt2 = (const float*)d_in[12];
  float* out = (float*)d_out;   // reference output dtype: float32

  char* p = (char*)d_ws;
  auto carve = [&](size_t bytes)->char*{ char* q = p; p += al256(bytes); return q; };
  float* W1T  = (float*)carve((size_t)1024 * 1024 * 4);   // [d=1024][e=1024]
  float* W2T  = (float*)carve((size_t)1024 * 512 * 4);    // [d=1024][e=512]
  float* mu0  = (float*)carve((size_t)128 * 1024 * 4);
  float* var0 = (float*)carve((size_t)128 * 1024 * 4);
  float* mu1  = (float*)carve((size_t)128 * 1024 * 4);
  float* var1 = (float*)carve((size_t)128 * 1024 * 4);
  float* mu2  = (float*)carve((size_t)128 * 512 * 4);
  float* var2 = (float*)carve((size_t)128 * 512 * 4);
  float* v0   = (float*)carve((size_t)32 * 1024 * 4);
  float* v1   = (float*)carve((size_t)32 * 1024 * 4);
  float* v2   = (float*)carve((size_t)32 * 512 * 4);
  size_t fixed_used = (size_t)(p - (char*)d_ws);

  auto need = [&](int nb)->size_t{
    return al256((size_t)nb * 256 * 1024 * 4)        // fp32 activation buffer
         + 2 * al256((size_t)nb * 256 * 16 * 8);     // mask0, mask1
  };
  int NB = 128;
  while (NB > 1 && fixed_used + need(NB) > ws_size) NB >>= 1;
  if (fixed_used + need(NB) > ws_size) return;

  float*              a_buf = (float*)carve((size_t)NB * 256 * 1024 * 4);
  unsigned long long* mask0 = (unsigned long long*)carve((size_t)NB * 256 * 16 * 8);
  unsigned long long* mask1 = (unsigned long long*)carve((size_t)NB * 256 * 16 * 8);

  // zero v-states (carved contiguously: 32*(1024+1024+512) floats)
  {
    int nz = 32 * (1024 + 1024 + 512);
    k_zero<<<dim3((nz + 255) / 256), dim3(256), 0, stream>>>((unsigned int*)v0, nz);
  }
  k_transpose<<<dim3(32, 32), dim3(32, 8), 0, stream>>>(W1, W1T, 1024, 1024);
  k_transpose<<<dim3(32, 16), dim3(32, 8), 0, stream>>>(W2, W2T, 512, 1024);

  int nblk = 128 / NB;
  for (int cb = 0; cb < nblk; ++cb){
    int c0 = cb * NB;
    int M = NB * 256;
    const float* xblk = x + (size_t)c0 * 256 * 512;

    // Layer 0 (Eigen-order FMA GEMM; n-tile-major grid for x L2 reuse)
    k_gemm_np<<<dim3(8, M / 256), dim3(256), 0, stream>>>(xblk, W0, b0, a_buf, M);
    k_stats_np<<<dim3(NB, 4), dim3(256), 0, stream>>>(a_buf, mu0, var0, 1024, c0);
    k_scan_spike_np<<<dim3(32 * 16), dim3(64), 0, stream>>>(a_buf, mu0, var0, g0, bt0, v0, mask0, 1024, c0, NB);

    // Layer 1 (sparse, ascending single-chain, batched loads)
    k_sparse_np<<<dim3(M), dim3(256), 0, stream>>>(mask0, W1T, b1, a_buf, 1024);
    k_stats_np<<<dim3(NB, 4), dim3(256), 0, stream>>>(a_buf, mu1, var1, 1024, c0);
    k_scan_spike_np<<<dim3(32 * 16), dim3(64), 0, stream>>>(a_buf, mu1, var1, g1, bt1, v1, mask1, 1024, c0, NB);

    // Layer 2 (sparse) + integrator output
    k_sparse_np<<<dim3(M / 2), dim3(256), 0, stream>>>(mask1, W2T, b2, a_buf, 512);
    k_stats_np<<<dim3(NB, 2), dim3(256), 0, stream>>>(a_buf, mu2, var2, 512, c0);
    k_scan_last_np<<<dim3(32 * 8), dim3(64), 0, stream>>>(a_buf, mu2, var2, g2, bt2, v2, out, c0, NB);
  }
}

// Round 10
// 1089.028 us; speedup vs baseline: 1.0628x; 1.0628x over previous
//
#include <hip/hip_runtime.h>
#include <hip/hip_bf16.h>
#include <stdint.h>

// SJ_SNN: bit-exact replica of the golden (jax on CPU -> XLA/Eigen fp32):
// per output element the contraction is a SINGLE accumulator, ascending k,
// true FMA. PASS r6..r12/r16 (absmax 0.00390625 = golden bf16 floor).
// r18 = r16 (GEMM = r10 verbatim, the verified 401us plateau) + rstd hoist:
//  - r17 16x8 tile REFUTED: VGPR spill (VGPR granule cap 128, scratch
//    traffic +127MB WRITE / +38MB FETCH, 483us). Two tile-upsize attempts
//    (r7, r17) both died on register pressure => 8x8/128^2 is the plateau.
//  - NEW: k_stats_np computes rstd = (float)(1.0/(double)sqrt((double)
//    (var+1e-5))) ONCE per (chunk,channel) and stores it in the var slot.
//    Previously each scan block recomputed this f64 sqrt+div for its own
//    sample: 32x duplication (~4.2M f64 pairs per hidden layer scan,
//    ~100us/scan at 0.5 waves/SIMD). Identical op sequence -> bit-exact.

__global__ void k_zero(unsigned int* __restrict__ p, int n){
  int i = blockIdx.x * 256 + threadIdx.x;
  if (i < n) p[i] = 0u;
}

// out[C][R] = in[R][C]  (exact fp32 copy)
__global__ void k_transpose(const float* __restrict__ in, float* __restrict__ out, int R, int C){
  __shared__ float tile[32][33];
  int bx = blockIdx.x * 32, by = blockIdx.y * 32;
  int tx = threadIdx.x, ty = threadIdx.y;
  for (int i = ty; i < 32; i += 8)
    tile[i][tx] = in[(size_t)(by + i) * C + bx + tx];
  __syncthreads();
  for (int i = ty; i < 32; i += 8)
    out[(size_t)(bx + i) * R + by + tx] = tile[tx][i];
}

// Layer-0 GEMM, Eigen order: C[m][e] = (single ascending FMA chain over
// k=0..511 of x[m][k]*W0[e][k]) + bias[e].
// 128(m) x 128(n) block tile, 8x8 per thread, 256 threads.  (r10 verified:
// ~401us, conflicts 1.05e6, WRITE 131MB. r11 SGPR-B and r17 16x8 both
// regressed: L1-port / VGPR-spill walls. This is the plateau structure.)
__global__ __launch_bounds__(256, 3) void k_gemm_np(const float* __restrict__ A,
    const float* __restrict__ Bw, const float* __restrict__ bias,
    float* __restrict__ C, int M){
  (void)M;
  __shared__ float As[32][132];
  __shared__ float Bs[32][132];
  int bm = blockIdx.y * 128;
  int bn = blockIdx.x * 128;
  int tid = threadIdx.x;
  int kk = tid & 31, q = tid >> 5;                 // staging decode (q 0..7)
  int c = (tid & 7) | ((tid & 64) >> 3);           // 0..15
  int r = ((tid >> 3) & 7) | ((tid & 128) >> 4);   // 0..15
  int giA = (2 * r) ^ (r >> 2);                    // G(k=0, col=r*8)
  int giB = (2 * c) ^ (c >> 2);                    // G(k=0, col=c*8)
  float acc[8][8];
#pragma unroll
  for (int ii = 0; ii < 8; ++ii)
#pragma unroll
    for (int jj = 0; jj < 8; ++jj) acc[ii][jj] = 0.f;

  for (int k0 = 0; k0 < 512; k0 += 32){
#pragma unroll
    for (int rr = 0; rr < 4; ++rr){
      int colb = q * 4 + rr * 32;                  // 4-aligned, 0..124
      int gi = (colb >> 2) ^ (colb >> 5) ^ (kk >> 3);
      float4 va, vb;
      va.x = A[(size_t)(bm + colb + 0) * 512 + k0 + kk];
      va.y = A[(size_t)(bm + colb + 1) * 512 + k0 + kk];
      va.z = A[(size_t)(bm + colb + 2) * 512 + k0 + kk];
      va.w = A[(size_t)(bm + colb + 3) * 512 + k0 + kk];
      vb.x = Bw[(size_t)(bn + colb + 0) * 512 + k0 + kk];
      vb.y = Bw[(size_t)(bn + colb + 1) * 512 + k0 + kk];
      vb.z = Bw[(size_t)(bn + colb + 2) * 512 + k0 + kk];
      vb.w = Bw[(size_t)(bn + colb + 3) * 512 + k0 + kk];
      *(float4*)&As[kk][gi << 2] = va;
      *(float4*)&Bs[kk][gi << 2] = vb;
    }
    __syncthreads();
#pragma unroll
    for (int kg = 0; kg < 4; ++kg){
      const int sa = (giA ^ kg) << 2;
      const int sb = (giB ^ kg) << 2;
#pragma unroll
      for (int k8 = 0; k8 < 8; ++k8){
        const int k = kg * 8 + k8;
        float4 av0 = *(const float4*)&As[k][sa];
        float4 av1 = *(const float4*)&As[k][sa ^ 4];
        float4 bv0 = *(const float4*)&Bs[k][sb];
        float4 bv1 = *(const float4*)&Bs[k][sb ^ 4];
        float a[8] = {av0.x, av0.y, av0.z, av0.w, av1.x, av1.y, av1.z, av1.w};
        float b[8] = {bv0.x, bv0.y, bv0.z, bv0.w, bv1.x, bv1.y, bv1.z, bv1.w};
#pragma unroll
        for (int ii = 0; ii < 8; ++ii)
#pragma unroll
          for (int jj = 0; jj < 8; ++jj)
            acc[ii][jj] = __fmaf_rn(a[ii], b[jj], acc[ii][jj]);
      }
    }
    __syncthreads();
  }

  // Epilogue: bias + LDS-staged coalesced stores (r10: avoids L2 RMW).
  float* S = &As[0][0];
  float4 bi0 = *(const float4*)(bias + bn + c * 8);
  float4 bi1 = *(const float4*)(bias + bn + c * 8 + 4);
  int rrow = tid >> 3;
  int f    = tid & 7;
  size_t mr = (size_t)(bm + (rrow >> 1) * 8 + (rrow & 1));
#pragma unroll
  for (int t4 = 0; t4 < 4; ++t4){
#pragma unroll
    for (int p = 0; p < 2; ++p){
      const int ii = t4 * 2 + p;
      const int row = r * 2 + p;
      const int giW = (2 * c) ^ (c >> 2) ^ (row >> 3);
      float4 o0, o1;
      o0.x = __fadd_rn(acc[ii][0], bi0.x);
      o0.y = __fadd_rn(acc[ii][1], bi0.y);
      o0.z = __fadd_rn(acc[ii][2], bi0.z);
      o0.w = __fadd_rn(acc[ii][3], bi0.w);
      o1.x = __fadd_rn(acc[ii][4], bi1.x);
      o1.y = __fadd_rn(acc[ii][5], bi1.y);
      o1.z = __fadd_rn(acc[ii][6], bi1.z);
      o1.w = __fadd_rn(acc[ii][7], bi1.w);
      *(float4*)&S[row * 132 + (giW << 2)] = o0;
      *(float4*)&S[row * 132 + ((giW << 2) ^ 4)] = o1;
    }
    __syncthreads();
#pragma unroll
    for (int u = 0; u < 4; ++u){
      int col4 = 4 * f + 32 * u;
      int giR = (f + 8 * u) ^ u ^ (rrow >> 3);
      float4 v = *(const float4*)&S[rrow * 132 + (giR << 2)];
      *(float4*)&C[(mr + (size_t)t4 * 2) * 1024 + bn + col4] = v;
    }
    __syncthreads();
  }
}

// BN stats: per (chunk, channel), SEQUENTIAL in-order over 256 samples.
// NEW (r18): also computes rstd = (float)(1.0/(double)sqrt((double)(var
// + 1e-5))) here, ONCE per (chunk,channel), and stores it in the second
// output buffer. Exact same fp op sequence the scans used -> bit-exact.
__global__ __launch_bounds__(256) void k_stats_np(const float* __restrict__ A,
    float* __restrict__ mu, float* __restrict__ rstd, int Dch, int c0){
  int cl = blockIdx.x;
  int ch = blockIdx.y * 256 + threadIdx.x;
  const float* base = A + (size_t)cl * 256 * Dch + ch;
  float acc = 0.f;
  for (int s = 0; s < 256; ++s)
    acc = __fadd_rn(acc, base[(size_t)s * Dch]);
  float m = __fmul_rn(acc, 1.f / 256.f);   // /256 exact (pow2)
  float vacc = 0.f;
  for (int s = 0; s < 256; ++s){
    float d = __fsub_rn(base[(size_t)s * Dch], m);
    vacc = __fadd_rn(vacc, __fmul_rn(d, d));
  }
  float var = __fmul_rn(vacc, 1.f / 256.f);
  float ve  = __fadd_rn(var, 1e-5f);
  float sq  = (float)sqrt((double)ve);         // correctly-rounded fp32 sqrt
  float r   = (float)(1.0 / (double)sq);       // correctly-rounded fp32 div
  int c = c0 + cl;
  mu[(size_t)c * Dch + ch]   = m;
  rstd[(size_t)c * Dch + ch] = r;
}

// fp32 BN + LIF scan (hidden layers): spike bitmasks, 64-thread blocks,
// software-pipelined chunk prefetch. rstd precomputed in stats (r18).
__global__ __launch_bounds__(64) void k_scan_spike_np(const float* __restrict__ A,
    const float* __restrict__ mu, const float* __restrict__ rstd,
    const float* __restrict__ g, const float* __restrict__ bt,
    float* __restrict__ vstate, unsigned long long* __restrict__ mask,
    int Dch, int c0, int nb){
  int ebn = Dch >> 6;
  int eb = blockIdx.x % ebn;
  int b  = blockIdx.x / ebn;
  int e  = (eb << 6) + threadIdx.x;
  float gg = g[e], bb = bt[e];
  float v = vstate[(size_t)b * Dch + e];
  float hbuf[8];
#pragma unroll
  for (int t = 0; t < 8; ++t)
    hbuf[t] = A[(size_t)(t * 32 + b) * Dch + e];
  for (int cl = 0; cl < nb; ++cl){
    int c = c0 + cl;
    float m = mu[(size_t)c * Dch + e];
    float r = rstd[(size_t)c * Dch + e];
    float hn[8];
    if (cl + 1 < nb){
#pragma unroll
      for (int t = 0; t < 8; ++t)
        hn[t] = A[(size_t)(((cl + 1) * 8 + t) * 32 + b) * Dch + e];
    } else {
#pragma unroll
      for (int t = 0; t < 8; ++t) hn[t] = 0.f;
    }
#pragma unroll
    for (int t = 0; t < 8; ++t){
      int sl = (cl * 8 + t) * 32 + b;
      float xn = __fadd_rn(__fmul_rn(__fmul_rn(gg, __fsub_rn(hbuf[t], m)), r), bb);
      v = __fadd_rn(v, __fmul_rn(__fsub_rn(xn, v), 0.5f));
      bool sp = (v >= 1.0f);                     // == (v-1>=0)
      unsigned long long bal = __ballot(sp);
      if (sp) v = 0.0f;
      if (threadIdx.x == 0) mask[(size_t)sl * 16 + eb] = bal;
    }
#pragma unroll
    for (int t = 0; t < 8; ++t) hbuf[t] = hn[t];
  }
  vstate[(size_t)b * Dch + e] = v;
}

// Sparse spike linear, Eigen order. Wave-cooperative list extraction:
// 16 lanes popcount their 64-bit mask word, __shfl exclusive prefix-scan,
// then parallel ascending writes into LDS. List order identical to the old
// serial scan -> single-accumulator ascending add chain preserved exactly.
// Consume loop: 8 weight rows in flight.
__global__ __launch_bounds__(256) void k_sparse_np(const unsigned long long* __restrict__ mask,
    const float* __restrict__ WT, const float* __restrict__ bias,
    float* __restrict__ C, int Dout){
  int tid = threadIdx.x;
  int lane = tid & 63;
  int wid = tid >> 6;
  int wps = Dout >> 8;            // waves per sample: 4 (1024) or 2 (512)
  int chgrp = wid % wps;
  int sgrp  = wid / wps;
  int spb   = 4 / wps;            // samples per block
  int s = blockIdx.x * spb + sgrp;
  int ch = (chgrp << 8) + (lane << 2);
  __shared__ unsigned short list[2][1024];
  __shared__ int nlist[2];

  if (chgrp == 0 && lane < 16){
    unsigned long long mw = mask[(size_t)s * 16 + lane];
    int cnt = __popcll(mw);
    int base = 0;
#pragma unroll
    for (int w = 0; w < 16; ++w){
      int cw = __shfl(cnt, w, 64);
      base += (w < lane) ? cw : 0;
    }
    int idx = base;
    while (mw){
      int bit = __ffsll(mw) - 1;
      mw &= mw - 1;
      list[sgrp][idx++] = (unsigned short)((lane << 6) + bit);
    }
    if (lane == 15) nlist[sgrp] = base + cnt;
  }
  __syncthreads();
  int n = nlist[sgrp];
  const unsigned short* il = list[sgrp];
  float a0 = 0.f, a1 = 0.f, a2 = 0.f, a3 = 0.f;
  int i = 0;
  for (; i + 8 <= n; i += 8){
    float4 wv[8];
#pragma unroll
    for (int u = 0; u < 8; ++u)
      wv[u] = *(const float4*)(WT + (size_t)il[i + u] * Dout + ch);
#pragma unroll
    for (int u = 0; u < 8; ++u){
      a0 = __fadd_rn(a0, wv[u].x); a1 = __fadd_rn(a1, wv[u].y);
      a2 = __fadd_rn(a2, wv[u].z); a3 = __fadd_rn(a3, wv[u].w);
    }
  }
  for (; i < n; ++i){
    int d = il[i];
    float4 wv = *(const float4*)(WT + (size_t)d * Dout + ch);
    a0 = __fadd_rn(a0, wv.x); a1 = __fadd_rn(a1, wv.y); a2 = __fadd_rn(a2, wv.z); a3 = __fadd_rn(a3, wv.w);
  }
  float4 bb = *(const float4*)(bias + ch);
  float4 o;
  o.x = __fadd_rn(a0, bb.x);
  o.y = __fadd_rn(a1, bb.y);
  o.z = __fadd_rn(a2, bb.z);
  o.w = __fadd_rn(a3, bb.w);
  *(float4*)(C + (size_t)s * Dout + ch) = o;
}

// Last layer: fp32 leaky integrator; sequential mean over 8 timesteps,
// /8 exact; float32 out. rstd precomputed in stats (r18).
__global__ __launch_bounds__(64) void k_scan_last_np(const float* __restrict__ A,
    const float* __restrict__ mu, const float* __restrict__ rstd,
    const float* __restrict__ g, const float* __restrict__ bt,
    float* __restrict__ vstate, float* __restrict__ out, int c0, int nb){
  const int Dch = 512;
  int eb = blockIdx.x & 7;
  int b  = blockIdx.x >> 3;
  int e  = (eb << 6) + threadIdx.x;
  float gg = g[e], bb = bt[e];
  float v = vstate[(size_t)b * Dch + e];
  float hbuf[8];
#pragma unroll
  for (int t = 0; t < 8; ++t)
    hbuf[t] = A[(size_t)(t * 32 + b) * Dch + e];
  for (int cl = 0; cl < nb; ++cl){
    int c = c0 + cl;
    float m = mu[(size_t)c * Dch + e];
    float r = rstd[(size_t)c * Dch + e];
    float hn[8];
    if (cl + 1 < nb){
#pragma unroll
      for (int t = 0; t < 8; ++t)
        hn[t] = A[(size_t)(((cl + 1) * 8 + t) * 32 + b) * Dch + e];
    } else {
#pragma unroll
      for (int t = 0; t < 8; ++t) hn[t] = 0.f;
    }
    float macc = 0.f;
#pragma unroll
    for (int t = 0; t < 8; ++t){
      float xn = __fadd_rn(__fmul_rn(__fmul_rn(gg, __fsub_rn(hbuf[t], m)), r), bb);
      v = __fadd_rn(v, __fmul_rn(__fsub_rn(xn, v), 0.5f));
      macc = __fadd_rn(macc, v);
    }
    out[((size_t)c * 32 + b) * 512 + e] = __fmul_rn(macc, 0.125f);
#pragma unroll
    for (int t = 0; t < 8; ++t) hbuf[t] = hn[t];
  }
  vstate[(size_t)b * Dch + e] = v;
}

static inline size_t al256(size_t x){ return (x + 255) & ~(size_t)255; }

extern "C" void kernel_launch(void* const* d_in, const int* in_sizes, int n_in,
                              void* d_out, int out_size, void* d_ws, size_t ws_size,
                              hipStream_t stream){
  (void)in_sizes; (void)n_in; (void)out_size;
  const float* x   = (const float*)d_in[0];
  const float* W0  = (const float*)d_in[1];
  const float* b0  = (const float*)d_in[2];
  const float* g0  = (const float*)d_in[3];
  const float* bt0 = (const float*)d_in[4];
  const float* W1  = (const float*)d_in[5];
  const float* b1  = (const float*)d_in[6];
  const float* g1  = (const float*)d_in[7];
  const float* bt1 = (const float*)d_in[8];
  const float* W2  = (const float*)d_in[9];
  const float* b2  = (const float*)d_in[10];
  const float* g2  = (const float*)d_in[11];
  const float* bt2 = (const float*)d_in[12];
  float* out = (float*)d_out;   // reference output dtype: float32

  char* p = (char*)d_ws;
  auto carve = [&](size_t bytes)->char*{ char* q = p; p += al256(bytes); return q; };
  float* W1T  = (float*)carve((size_t)1024 * 1024 * 4);   // [d=1024][e=1024]
  float* W2T  = (float*)carve((size_t)1024 * 512 * 4);    // [d=1024][e=512]
  float* mu0  = (float*)carve((size_t)128 * 1024 * 4);
  float* rs0  = (float*)carve((size_t)128 * 1024 * 4);
  float* mu1  = (float*)carve((size_t)128 * 1024 * 4);
  float* rs1  = (float*)carve((size_t)128 * 1024 * 4);
  float* mu2  = (float*)carve((size_t)128 * 512 * 4);
  float* rs2  = (float*)carve((size_t)128 * 512 * 4);
  float* v0   = (float*)carve((size_t)32 * 1024 * 4);
  float* v1   = (float*)carve((size_t)32 * 1024 * 4);
  float* v2   = (float*)carve((size_t)32 * 512 * 4);
  size_t fixed_used = (size_t)(p - (char*)d_ws);

  auto need = [&](int nb)->size_t{
    return al256((size_t)nb * 256 * 1024 * 4)        // fp32 activation buffer
         + 2 * al256((size_t)nb * 256 * 16 * 8);     // mask0, mask1
  };
  int NB = 128;
  while (NB > 1 && fixed_used + need(NB) > ws_size) NB >>= 1;
  if (fixed_used + need(NB) > ws_size) return;

  float*              a_buf = (float*)carve((size_t)NB * 256 * 1024 * 4);
  unsigned long long* mask0 = (unsigned long long*)carve((size_t)NB * 256 * 16 * 8);
  unsigned long long* mask1 = (unsigned long long*)carve((size_t)NB * 256 * 16 * 8);

  // zero v-states (carved contiguously: 32*(1024+1024+512) floats)
  {
    int nz = 32 * (1024 + 1024 + 512);
    k_zero<<<dim3((nz + 255) / 256), dim3(256), 0, stream>>>((unsigned int*)v0, nz);
  }
  k_transpose<<<dim3(32, 32), dim3(32, 8), 0, stream>>>(W1, W1T, 1024, 1024);
  k_transpose<<<dim3(32, 16), dim3(32, 8), 0, stream>>>(W2, W2T, 512, 1024);

  int nblk = 128 / NB;
  for (int cb = 0; cb < nblk; ++cb){
    int c0 = cb * NB;
    int M = NB * 256;
    const float* xblk = x + (size_t)c0 * 256 * 512;

    // Layer 0 (Eigen-order FMA GEMM; n-tile-major grid for x L2 reuse)
    k_gemm_np<<<dim3(8, M / 128), dim3(256), 0, stream>>>(xblk, W0, b0, a_buf, M);
    k_stats_np<<<dim3(NB, 4), dim3(256), 0, stream>>>(a_buf, mu0, rs0, 1024, c0);
    k_scan_spike_np<<<dim3(32 * 16), dim3(64), 0, stream>>>(a_buf, mu0, rs0, g0, bt0, v0, mask0, 1024, c0, NB);

    // Layer 1 (sparse, ascending single-chain, batched loads)
    k_sparse_np<<<dim3(M), dim3(256), 0, stream>>>(mask0, W1T, b1, a_buf, 1024);
    k_stats_np<<<dim3(NB, 4), dim3(256), 0, stream>>>(a_buf, mu1, rs1, 1024, c0);
    k_scan_spike_np<<<dim3(32 * 16), dim3(64), 0, stream>>>(a_buf, mu1, rs1, g1, bt1, v1, mask1, 1024, c0, NB);

    // Layer 2 (sparse) + integrator output
    k_sparse_np<<<dim3(M / 2), dim3(256), 0, stream>>>(mask1, W2T, b2, a_buf, 512);
    k_stats_np<<<dim3(NB, 2), dim3(256), 0, stream>>>(a_buf, mu2, rs2, 512, c0);
    k_scan_last_np<<<dim3(32 * 8), dim3(64), 0, stream>>>(a_buf, mu2, rs2, g2, bt2, v2, out, c0, NB);
  }
}

// Round 11
// 1038.386 us; speedup vs baseline: 1.1147x; 1.0488x over previous
//
#include <hip/hip_runtime.h>
#include <hip/hip_bf16.h>
#include <stdint.h>

// SJ_SNN: bit-exact replica of the golden (jax on CPU -> XLA/Eigen fp32):
// per output element the contraction is a SINGLE accumulator, ascending k,
// true FMA. PASS r6..r12/r16/r18 (absmax 0.00390625 = golden bf16 floor).
// r19 = r18 + two latency levers (no structural changes):
//  (1) GEMM __launch_bounds__(256,3) -> (256,4): 4 blocks/CU (LDS 135KB<160,
//      VGPR 64<=128 cap). Blocks barrier independently -> co-resident blocks
//      hide each other's __syncthreads drain (26% idle at 3 blocks).
//  (2) scans: 2-phase even/odd chunk loop (named bufs hA/hB, rule #20 safe)
//      prefetching next chunk's h AND mu/rstd before processing current ->
//      removes ~300cyc L2 stall per chunk. Load scheduling only; compute
//      order identical -> bit-exact.
// History: r17 16x8 tile refuted (VGPR spill); r13/r15 grouped-sparse
// refuted (predication = dense); r11 SGPR-B refuted (L1 port). GEMM 8x8
// structure + r10 swizzle is the plateau; sparse ~420us is at L2-BW floor.

__global__ void k_zero(unsigned int* __restrict__ p, int n){
  int i = blockIdx.x * 256 + threadIdx.x;
  if (i < n) p[i] = 0u;
}

// out[C][R] = in[R][C]  (exact fp32 copy)
__global__ void k_transpose(const float* __restrict__ in, float* __restrict__ out, int R, int C){
  __shared__ float tile[32][33];
  int bx = blockIdx.x * 32, by = blockIdx.y * 32;
  int tx = threadIdx.x, ty = threadIdx.y;
  for (int i = ty; i < 32; i += 8)
    tile[i][tx] = in[(size_t)(by + i) * C + bx + tx];
  __syncthreads();
  for (int i = ty; i < 32; i += 8)
    out[(size_t)(bx + i) * R + by + tx] = tile[tx][i];
}

// Layer-0 GEMM, Eigen order: C[m][e] = (single ascending FMA chain over
// k=0..511 of x[m][k]*W0[e][k]) + bias[e].
// 128(m) x 128(n) block tile, 8x8 per thread, 256 threads. (r10 structure,
// verified 401-405us; r19: occupancy 3->4 blocks/CU.)
__global__ __launch_bounds__(256, 4) void k_gemm_np(const float* __restrict__ A,
    const float* __restrict__ Bw, const float* __restrict__ bias,
    float* __restrict__ C, int M){
  (void)M;
  __shared__ float As[32][132];
  __shared__ float Bs[32][132];
  int bm = blockIdx.y * 128;
  int bn = blockIdx.x * 128;
  int tid = threadIdx.x;
  int kk = tid & 31, q = tid >> 5;                 // staging decode (q 0..7)
  int c = (tid & 7) | ((tid & 64) >> 3);           // 0..15
  int r = ((tid >> 3) & 7) | ((tid & 128) >> 4);   // 0..15
  int giA = (2 * r) ^ (r >> 2);                    // G(k=0, col=r*8)
  int giB = (2 * c) ^ (c >> 2);                    // G(k=0, col=c*8)
  float acc[8][8];
#pragma unroll
  for (int ii = 0; ii < 8; ++ii)
#pragma unroll
    for (int jj = 0; jj < 8; ++jj) acc[ii][jj] = 0.f;

  for (int k0 = 0; k0 < 512; k0 += 32){
#pragma unroll
    for (int rr = 0; rr < 4; ++rr){
      int colb = q * 4 + rr * 32;                  // 4-aligned, 0..124
      int gi = (colb >> 2) ^ (colb >> 5) ^ (kk >> 3);
      float4 va, vb;
      va.x = A[(size_t)(bm + colb + 0) * 512 + k0 + kk];
      va.y = A[(size_t)(bm + colb + 1) * 512 + k0 + kk];
      va.z = A[(size_t)(bm + colb + 2) * 512 + k0 + kk];
      va.w = A[(size_t)(bm + colb + 3) * 512 + k0 + kk];
      vb.x = Bw[(size_t)(bn + colb + 0) * 512 + k0 + kk];
      vb.y = Bw[(size_t)(bn + colb + 1) * 512 + k0 + kk];
      vb.z = Bw[(size_t)(bn + colb + 2) * 512 + k0 + kk];
      vb.w = Bw[(size_t)(bn + colb + 3) * 512 + k0 + kk];
      *(float4*)&As[kk][gi << 2] = va;
      *(float4*)&Bs[kk][gi << 2] = vb;
    }
    __syncthreads();
#pragma unroll
    for (int kg = 0; kg < 4; ++kg){
      const int sa = (giA ^ kg) << 2;
      const int sb = (giB ^ kg) << 2;
#pragma unroll
      for (int k8 = 0; k8 < 8; ++k8){
        const int k = kg * 8 + k8;
        float4 av0 = *(const float4*)&As[k][sa];
        float4 av1 = *(const float4*)&As[k][sa ^ 4];
        float4 bv0 = *(const float4*)&Bs[k][sb];
        float4 bv1 = *(const float4*)&Bs[k][sb ^ 4];
        float a[8] = {av0.x, av0.y, av0.z, av0.w, av1.x, av1.y, av1.z, av1.w};
        float b[8] = {bv0.x, bv0.y, bv0.z, bv0.w, bv1.x, bv1.y, bv1.z, bv1.w};
#pragma unroll
        for (int ii = 0; ii < 8; ++ii)
#pragma unroll
          for (int jj = 0; jj < 8; ++jj)
            acc[ii][jj] = __fmaf_rn(a[ii], b[jj], acc[ii][jj]);
      }
    }
    __syncthreads();
  }

  // Epilogue: bias + LDS-staged coalesced stores (r10: avoids L2 RMW).
  float* S = &As[0][0];
  float4 bi0 = *(const float4*)(bias + bn + c * 8);
  float4 bi1 = *(const float4*)(bias + bn + c * 8 + 4);
  int rrow = tid >> 3;
  int f    = tid & 7;
  size_t mr = (size_t)(bm + (rrow >> 1) * 8 + (rrow & 1));
#pragma unroll
  for (int t4 = 0; t4 < 4; ++t4){
#pragma unroll
    for (int p = 0; p < 2; ++p){
      const int ii = t4 * 2 + p;
      const int row = r * 2 + p;
      const int giW = (2 * c) ^ (c >> 2) ^ (row >> 3);
      float4 o0, o1;
      o0.x = __fadd_rn(acc[ii][0], bi0.x);
      o0.y = __fadd_rn(acc[ii][1], bi0.y);
      o0.z = __fadd_rn(acc[ii][2], bi0.z);
      o0.w = __fadd_rn(acc[ii][3], bi0.w);
      o1.x = __fadd_rn(acc[ii][4], bi1.x);
      o1.y = __fadd_rn(acc[ii][5], bi1.y);
      o1.z = __fadd_rn(acc[ii][6], bi1.z);
      o1.w = __fadd_rn(acc[ii][7], bi1.w);
      *(float4*)&S[row * 132 + (giW << 2)] = o0;
      *(float4*)&S[row * 132 + ((giW << 2) ^ 4)] = o1;
    }
    __syncthreads();
#pragma unroll
    for (int u = 0; u < 4; ++u){
      int col4 = 4 * f + 32 * u;
      int giR = (f + 8 * u) ^ u ^ (rrow >> 3);
      float4 v = *(const float4*)&S[rrow * 132 + (giR << 2)];
      *(float4*)&C[(mr + (size_t)t4 * 2) * 1024 + bn + col4] = v;
    }
    __syncthreads();
  }
}

// BN stats: per (chunk, channel), SEQUENTIAL in-order over 256 samples.
// Computes rstd once per (chunk,channel) (r18 hoist) -> bit-exact.
__global__ __launch_bounds__(256) void k_stats_np(const float* __restrict__ A,
    float* __restrict__ mu, float* __restrict__ rstd, int Dch, int c0){
  int cl = blockIdx.x;
  int ch = blockIdx.y * 256 + threadIdx.x;
  const float* base = A + (size_t)cl * 256 * Dch + ch;
  float acc = 0.f;
  for (int s = 0; s < 256; ++s)
    acc = __fadd_rn(acc, base[(size_t)s * Dch]);
  float m = __fmul_rn(acc, 1.f / 256.f);   // /256 exact (pow2)
  float vacc = 0.f;
  for (int s = 0; s < 256; ++s){
    float d = __fsub_rn(base[(size_t)s * Dch], m);
    vacc = __fadd_rn(vacc, __fmul_rn(d, d));
  }
  float var = __fmul_rn(vacc, 1.f / 256.f);
  float ve  = __fadd_rn(var, 1e-5f);
  float sq  = (float)sqrt((double)ve);         // correctly-rounded fp32 sqrt
  float r   = (float)(1.0 / (double)sq);       // correctly-rounded fp32 div
  int c = c0 + cl;
  mu[(size_t)c * Dch + ch]   = m;
  rstd[(size_t)c * Dch + ch] = r;
}

// fp32 BN + LIF scan (hidden layers): spike bitmasks, 64-thread blocks.
// r19: 2-phase even/odd chunk loop; next chunk's h + mu/rstd prefetched
// before processing current chunk (pure load scheduling; bit-exact).
__global__ __launch_bounds__(64) void k_scan_spike_np(const float* __restrict__ A,
    const float* __restrict__ mu, const float* __restrict__ rstd,
    const float* __restrict__ g, const float* __restrict__ bt,
    float* __restrict__ vstate, unsigned long long* __restrict__ mask,
    int Dch, int c0, int nb){
  int ebn = Dch >> 6;
  int eb = blockIdx.x % ebn;
  int b  = blockIdx.x / ebn;
  int e  = (eb << 6) + threadIdx.x;
  float gg = g[e], bb = bt[e];
  float v = vstate[(size_t)b * Dch + e];
  float hA[8], hB[8];
#pragma unroll
  for (int t = 0; t < 8; ++t)
    hA[t] = A[(size_t)(t * 32 + b) * Dch + e];
  float mN = mu[(size_t)c0 * Dch + e];
  float rN = rstd[(size_t)c0 * Dch + e];

  for (int cl = 0; cl < nb; cl += 2){
    // ---- even chunk cl: consumes hA, mN/rN; prefetch chunk cl+1 ----
    {
      float mC = mN, rC = rN;
      if (cl + 1 < nb){
#pragma unroll
        for (int t = 0; t < 8; ++t)
          hB[t] = A[(size_t)(((cl + 1) * 8 + t) * 32 + b) * Dch + e];
        mN = mu[(size_t)(c0 + cl + 1) * Dch + e];
        rN = rstd[(size_t)(c0 + cl + 1) * Dch + e];
      }
#pragma unroll
      for (int t = 0; t < 8; ++t){
        int sl = (cl * 8 + t) * 32 + b;
        float xn = __fadd_rn(__fmul_rn(__fmul_rn(gg, __fsub_rn(hA[t], mC)), rC), bb);
        v = __fadd_rn(v, __fmul_rn(__fsub_rn(xn, v), 0.5f));
        bool sp = (v >= 1.0f);                   // == (v-1>=0)
        unsigned long long bal = __ballot(sp);
        if (sp) v = 0.0f;
        if (threadIdx.x == 0) mask[(size_t)sl * 16 + eb] = bal;
      }
    }
    // ---- odd chunk cl+1: consumes hB, mN/rN; prefetch chunk cl+2 ----
    if (cl + 1 < nb){
      float mC = mN, rC = rN;
      if (cl + 2 < nb){
#pragma unroll
        for (int t = 0; t < 8; ++t)
          hA[t] = A[(size_t)(((cl + 2) * 8 + t) * 32 + b) * Dch + e];
        mN = mu[(size_t)(c0 + cl + 2) * Dch + e];
        rN = rstd[(size_t)(c0 + cl + 2) * Dch + e];
      }
#pragma unroll
      for (int t = 0; t < 8; ++t){
        int sl = ((cl + 1) * 8 + t) * 32 + b;
        float xn = __fadd_rn(__fmul_rn(__fmul_rn(gg, __fsub_rn(hB[t], mC)), rC), bb);
        v = __fadd_rn(v, __fmul_rn(__fsub_rn(xn, v), 0.5f));
        bool sp = (v >= 1.0f);
        unsigned long long bal = __ballot(sp);
        if (sp) v = 0.0f;
        if (threadIdx.x == 0) mask[(size_t)sl * 16 + eb] = bal;
      }
    }
  }
  vstate[(size_t)b * Dch + e] = v;
}

// Sparse spike linear, Eigen order. Wave-cooperative list extraction:
// 16 lanes popcount their 64-bit mask word, __shfl exclusive prefix-scan,
// then parallel ascending writes into LDS. List order identical to the old
// serial scan -> single-accumulator ascending add chain preserved exactly.
// Consume loop: 8 weight rows in flight.
__global__ __launch_bounds__(256) void k_sparse_np(const unsigned long long* __restrict__ mask,
    const float* __restrict__ WT, const float* __restrict__ bias,
    float* __restrict__ C, int Dout){
  int tid = threadIdx.x;
  int lane = tid & 63;
  int wid = tid >> 6;
  int wps = Dout >> 8;            // waves per sample: 4 (1024) or 2 (512)
  int chgrp = wid % wps;
  int sgrp  = wid / wps;
  int spb   = 4 / wps;            // samples per block
  int s = blockIdx.x * spb + sgrp;
  int ch = (chgrp << 8) + (lane << 2);
  __shared__ unsigned short list[2][1024];
  __shared__ int nlist[2];

  if (chgrp == 0 && lane < 16){
    unsigned long long mw = mask[(size_t)s * 16 + lane];
    int cnt = __popcll(mw);
    int base = 0;
#pragma unroll
    for (int w = 0; w < 16; ++w){
      int cw = __shfl(cnt, w, 64);
      base += (w < lane) ? cw : 0;
    }
    int idx = base;
    while (mw){
      int bit = __ffsll(mw) - 1;
      mw &= mw - 1;
      list[sgrp][idx++] = (unsigned short)((lane << 6) + bit);
    }
    if (lane == 15) nlist[sgrp] = base + cnt;
  }
  __syncthreads();
  int n = nlist[sgrp];
  const unsigned short* il = list[sgrp];
  float a0 = 0.f, a1 = 0.f, a2 = 0.f, a3 = 0.f;
  int i = 0;
  for (; i + 8 <= n; i += 8){
    float4 wv[8];
#pragma unroll
    for (int u = 0; u < 8; ++u)
      wv[u] = *(const float4*)(WT + (size_t)il[i + u] * Dout + ch);
#pragma unroll
    for (int u = 0; u < 8; ++u){
      a0 = __fadd_rn(a0, wv[u].x); a1 = __fadd_rn(a1, wv[u].y);
      a2 = __fadd_rn(a2, wv[u].z); a3 = __fadd_rn(a3, wv[u].w);
    }
  }
  for (; i < n; ++i){
    int d = il[i];
    float4 wv = *(const float4*)(WT + (size_t)d * Dout + ch);
    a0 = __fadd_rn(a0, wv.x); a1 = __fadd_rn(a1, wv.y); a2 = __fadd_rn(a2, wv.z); a3 = __fadd_rn(a3, wv.w);
  }
  float4 bb = *(const float4*)(bias + ch);
  float4 o;
  o.x = __fadd_rn(a0, bb.x);
  o.y = __fadd_rn(a1, bb.y);
  o.z = __fadd_rn(a2, bb.z);
  o.w = __fadd_rn(a3, bb.w);
  *(float4*)(C + (size_t)s * Dout + ch) = o;
}

// Last layer: fp32 leaky integrator; sequential mean over 8 timesteps,
// /8 exact; float32 out. r19: same 2-phase prefetch as spike scan.
__global__ __launch_bounds__(64) void k_scan_last_np(const float* __restrict__ A,
    const float* __restrict__ mu, const float* __restrict__ rstd,
    const float* __restrict__ g, const float* __restrict__ bt,
    float* __restrict__ vstate, float* __restrict__ out, int c0, int nb){
  const int Dch = 512;
  int eb = blockIdx.x & 7;
  int b  = blockIdx.x >> 3;
  int e  = (eb << 6) + threadIdx.x;
  float gg = g[e], bb = bt[e];
  float v = vstate[(size_t)b * Dch + e];
  float hA[8], hB[8];
#pragma unroll
  for (int t = 0; t < 8; ++t)
    hA[t] = A[(size_t)(t * 32 + b) * Dch + e];
  float mN = mu[(size_t)c0 * Dch + e];
  float rN = rstd[(size_t)c0 * Dch + e];

  for (int cl = 0; cl < nb; cl += 2){
    // ---- even chunk cl ----
    {
      float mC = mN, rC = rN;
      if (cl + 1 < nb){
#pragma unroll
        for (int t = 0; t < 8; ++t)
          hB[t] = A[(size_t)(((cl + 1) * 8 + t) * 32 + b) * Dch + e];
        mN = mu[(size_t)(c0 + cl + 1) * Dch + e];
        rN = rstd[(size_t)(c0 + cl + 1) * Dch + e];
      }
      float macc = 0.f;
#pragma unroll
      for (int t = 0; t < 8; ++t){
        float xn = __fadd_rn(__fmul_rn(__fmul_rn(gg, __fsub_rn(hA[t], mC)), rC), bb);
        v = __fadd_rn(v, __fmul_rn(__fsub_rn(xn, v), 0.5f));
        macc = __fadd_rn(macc, v);
      }
      out[((size_t)(c0 + cl) * 32 + b) * 512 + e] = __fmul_rn(macc, 0.125f);
    }
    // ---- odd chunk cl+1 ----
    if (cl + 1 < nb){
      float mC = mN, rC = rN;
      if (cl + 2 < nb){
#pragma unroll
        for (int t = 0; t < 8; ++t)
          hA[t] = A[(size_t)(((cl + 2) * 8 + t) * 32 + b) * Dch + e];
        mN = mu[(size_t)(c0 + cl + 2) * Dch + e];
        rN = rstd[(size_t)(c0 + cl + 2) * Dch + e];
      }
      float macc = 0.f;
#pragma unroll
      for (int t = 0; t < 8; ++t){
        float xn = __fadd_rn(__fmul_rn(__fmul_rn(gg, __fsub_rn(hB[t], mC)), rC), bb);
        v = __fadd_rn(v, __fmul_rn(__fsub_rn(xn, v), 0.5f));
        macc = __fadd_rn(macc, v);
      }
      out[((size_t)(c0 + cl + 1) * 32 + b) * 512 + e] = __fmul_rn(macc, 0.125f);
    }
  }
  vstate[(size_t)b * Dch + e] = v;
}

static inline size_t al256(size_t x){ return (x + 255) & ~(size_t)255; }

extern "C" void kernel_launch(void* const* d_in, const int* in_sizes, int n_in,
                              void* d_out, int out_size, void* d_ws, size_t ws_size,
                              hipStream_t stream){
  (void)in_sizes; (void)n_in; (void)out_size;
  const float* x   = (const float*)d_in[0];
  const float* W0  = (const float*)d_in[1];
  const float* b0  = (const float*)d_in[2];
  const float* g0  = (const float*)d_in[3];
  const float* bt0 = (const float*)d_in[4];
  const float* W1  = (const float*)d_in[5];
  const float* b1  = (const float*)d_in[6];
  const float* g1  = (const float*)d_in[7];
  const float* bt1 = (const float*)d_in[8];
  const float* W2  = (const float*)d_in[9];
  const float* b2  = (const float*)d_in[10];
  const float* g2  = (const float*)d_in[11];
  const float* bt2 = (const float*)d_in[12];
  float* out = (float*)d_out;   // reference output dtype: float32

  char* p = (char*)d_ws;
  auto carve = [&](size_t bytes)->char*{ char* q = p; p += al256(bytes); return q; };
  float* W1T  = (float*)carve((size_t)1024 * 1024 * 4);   // [d=1024][e=1024]
  float* W2T  = (float*)carve((size_t)1024 * 512 * 4);    // [d=1024][e=512]
  float* mu0  = (float*)carve((size_t)128 * 1024 * 4);
  float* rs0  = (float*)carve((size_t)128 * 1024 * 4);
  float* mu1  = (float*)carve((size_t)128 * 1024 * 4);
  float* rs1  = (float*)carve((size_t)128 * 1024 * 4);
  float* mu2  = (float*)carve((size_t)128 * 512 * 4);
  float* rs2  = (float*)carve((size_t)128 * 512 * 4);
  float* v0   = (float*)carve((size_t)32 * 1024 * 4);
  float* v1   = (float*)carve((size_t)32 * 1024 * 4);
  float* v2   = (float*)carve((size_t)32 * 512 * 4);
  size_t fixed_used = (size_t)(p - (char*)d_ws);

  auto need = [&](int nb)->size_t{
    return al256((size_t)nb * 256 * 1024 * 4)        // fp32 activation buffer
         + 2 * al256((size_t)nb * 256 * 16 * 8);     // mask0, mask1
  };
  int NB = 128;
  while (NB > 1 && fixed_used + need(NB) > ws_size) NB >>= 1;
  if (fixed_used + need(NB) > ws_size) return;

  float*              a_buf = (float*)carve((size_t)NB * 256 * 1024 * 4);
  unsigned long long* mask0 = (unsigned long long*)carve((size_t)NB * 256 * 16 * 8);
  unsigned long long* mask1 = (unsigned long long*)carve((size_t)NB * 256 * 16 * 8);

  // zero v-states (carved contiguously: 32*(1024+1024+512) floats)
  {
    int nz = 32 * (1024 + 1024 + 512);
    k_zero<<<dim3((nz + 255) / 256), dim3(256), 0, stream>>>((unsigned int*)v0, nz);
  }
  k_transpose<<<dim3(32, 32), dim3(32, 8), 0, stream>>>(W1, W1T, 1024, 1024);
  k_transpose<<<dim3(32, 16), dim3(32, 8), 0, stream>>>(W2, W2T, 512, 1024);

  int nblk = 128 / NB;
  for (int cb = 0; cb < nblk; ++cb){
    int c0 = cb * NB;
    int M = NB * 256;
    const float* xblk = x + (size_t)c0 * 256 * 512;

    // Layer 0 (Eigen-order FMA GEMM; n-tile-major grid for x L2 reuse)
    k_gemm_np<<<dim3(8, M / 128), dim3(256), 0, stream>>>(xblk, W0, b0, a_buf, M);
    k_stats_np<<<dim3(NB, 4), dim3(256), 0, stream>>>(a_buf, mu0, rs0, 1024, c0);
    k_scan_spike_np<<<dim3(32 * 16), dim3(64), 0, stream>>>(a_buf, mu0, rs0, g0, bt0, v0, mask0, 1024, c0, NB);

    // Layer 1 (sparse, ascending single-chain, batched loads)
    k_sparse_np<<<dim3(M), dim3(256), 0, stream>>>(mask0, W1T, b1, a_buf, 1024);
    k_stats_np<<<dim3(NB, 4), dim3(256), 0, stream>>>(a_buf, mu1, rs1, 1024, c0);
    k_scan_spike_np<<<dim3(32 * 16), dim3(64), 0, stream>>>(a_buf, mu1, rs1, g1, bt1, v1, mask1, 1024, c0, NB);

    // Layer 2 (sparse) + integrator output
    k_sparse_np<<<dim3(M / 2), dim3(256), 0, stream>>>(mask1, W2T, b2, a_buf, 512);
    k_stats_np<<<dim3(NB, 2), dim3(256), 0, stream>>>(a_buf, mu2, rs2, 512, c0);
    k_scan_last_np<<<dim3(32 * 8), dim3(64), 0, stream>>>(a_buf, mu2, rs2, g2, bt2, v2, out, c0, NB);
  }
}